// Round 1
// baseline (938.563 us; speedup 1.0000x reference)
//
#include <hip/hip_runtime.h>
#include <hip/hip_bf16.h>

// ---------- helpers ----------
__device__ __forceinline__ float bf2f(ushort u) {
    union { unsigned int i; float f; } v; v.i = ((unsigned int)u) << 16; return v.f;
}
__device__ __forceinline__ ushort f2bf(float f) {
    union { float f; unsigned int i; } v; v.f = f;
    unsigned int x = v.i;
    unsigned int r = (x + 0x7fffu + ((x >> 16) & 1u)) >> 16;   // RNE
    return (ushort)r;
}

// ---------- small utility kernels ----------
__global__ void zero_i32(int* p, int n) {
    int i = blockIdx.x * blockDim.x + threadIdx.x;
    if (i < n) p[i] = 0;
}

__global__ void cvt_f32_bf16(const float4* __restrict__ in, ushort4* __restrict__ out, int n4) {
    int i = blockIdx.x * blockDim.x + threadIdx.x;
    int stride = gridDim.x * blockDim.x;
    for (; i < n4; i += stride) {
        float4 f = in[i];
        ushort4 o;
        o.x = f2bf(f.x); o.y = f2bf(f.y); o.z = f2bf(f.z); o.w = f2bf(f.w);
        out[i] = o;
    }
}

__global__ void deg_kernel(const int* __restrict__ dst, int* __restrict__ deg, int E) {
    int e = blockIdx.x * blockDim.x + threadIdx.x;
    if (e < E) atomicAdd(&deg[dst[e]], 1);
}

// block-wise exclusive scan over deg (256 elems/block)
__global__ void scan1(const int* __restrict__ deg, int* __restrict__ excl,
                      int* __restrict__ bsum, int N) {
    __shared__ int s[256];
    int tid = threadIdx.x;
    int gid = blockIdx.x * 256 + tid;
    int v = (gid < N) ? deg[gid] : 0;
    s[tid] = v;
    __syncthreads();
    for (int off = 1; off < 256; off <<= 1) {
        int t = (tid >= off) ? s[tid - off] : 0;
        __syncthreads();
        s[tid] += t;
        __syncthreads();
    }
    if (gid < N) excl[gid] = s[tid] - v;
    if (tid == 255) bsum[blockIdx.x] = s[255];
}

// single block, exclusive scan of up to 512 block sums (in place)
__global__ void scan2(int* __restrict__ bsum, int nb) {
    __shared__ int s[512];
    int tid = threadIdx.x;
    int v = (tid < nb) ? bsum[tid] : 0;
    s[tid] = v;
    __syncthreads();
    for (int off = 1; off < 512; off <<= 1) {
        int t = (tid >= off) ? s[tid - off] : 0;
        __syncthreads();
        s[tid] += t;
        __syncthreads();
    }
    if (tid < nb) bsum[tid] = s[tid] - v;
}

__global__ void add_off(int* __restrict__ offs, const int* __restrict__ bsum,
                        int* __restrict__ cursor, int N, int E) {
    int gid = blockIdx.x * blockDim.x + threadIdx.x;
    if (gid < N) {
        int o = offs[gid] + bsum[gid >> 8];
        offs[gid] = o;
        cursor[gid] = o;
    } else if (gid == N) {
        offs[N] = E;
    }
}

__global__ void fill_csr(const int* __restrict__ src, const int* __restrict__ dst,
                         int* __restrict__ cursor, int* __restrict__ csr, int E) {
    int e = blockIdx.x * blockDim.x + threadIdx.x;
    if (e < E) {
        int p = atomicAdd(&cursor[dst[e]], 1);
        csr[p] = src[e];
    }
}

// ---------- mean aggregation (one wave per node) ----------
template <int D>
__global__ void agg_mean(const ushort* __restrict__ h, const int* __restrict__ off,
                         const int* __restrict__ csr, ushort* __restrict__ out) {
    constexpr int V = D / 64;  // bf16 elems per lane (2 or 4)
    int n = blockIdx.x;
    int lane = threadIdx.x;  // 64 threads
    int s = off[n], e = off[n + 1];
    float acc[V];
#pragma unroll
    for (int k = 0; k < V; ++k) acc[k] = 0.f;
    for (int i = s; i < e; ++i) {
        int u = csr[i];
        if constexpr (V == 2) {
            ushort2 q = *reinterpret_cast<const ushort2*>(h + (size_t)u * D + lane * 2);
            acc[0] += bf2f(q.x); acc[1] += bf2f(q.y);
        } else {
            ushort4 q = *reinterpret_cast<const ushort4*>(h + (size_t)u * D + lane * 4);
            acc[0] += bf2f(q.x); acc[1] += bf2f(q.y);
            acc[2] += bf2f(q.z); acc[3] += bf2f(q.w);
        }
    }
    float inv = (e > s) ? 1.0f / (float)(e - s) : 1.0f;
    if constexpr (V == 2) {
        ushort2 o;
        o.x = f2bf(acc[0] * inv); o.y = f2bf(acc[1] * inv);
        *reinterpret_cast<ushort2*>(out + (size_t)n * D + lane * 2) = o;
    } else {
        ushort4 o;
        o.x = f2bf(acc[0] * inv); o.y = f2bf(acc[1] * inv);
        o.z = f2bf(acc[2] * inv); o.w = f2bf(acc[3] * inv);
        *reinterpret_cast<ushort4*>(out + (size_t)n * D + lane * 4) = o;
    }
}

// ---------- fused GEMM: out = act( A1@W1 [+ A2@W2] + bias ) ----------
// A: bf16 [M x K] row-major; W: fp32 [K x NC] row-major.
// ACT: 0 = none (fp32 out), 1 = relu (bf16 out), 2 = bn+relu (bf16 out)
template <int K, int NC, bool TWOA, int ACT>
__launch_bounds__(256)
__global__ void gemm_fused(const ushort* __restrict__ A1, const ushort* __restrict__ A2,
                           const float* __restrict__ W1g, const float* __restrict__ W2g,
                           const float* __restrict__ bias, const float* __restrict__ gamma,
                           const float* __restrict__ beta,
                           ushort* __restrict__ outb, float* __restrict__ outf, int M) {
    __shared__ float As[32][68];  // k-major: As[kk][row]
    __shared__ float Ws[32][68];  // Ws[kk][col]
    const int tid = threadIdx.x;
    const int tx = tid & 15, ty = tid >> 4;
    const int m0 = blockIdx.x * 64, n0 = blockIdx.y * 64;

    float acc[4][4];
#pragma unroll
    for (int i = 0; i < 4; ++i)
#pragma unroll
        for (int j = 0; j < 4; ++j) acc[i][j] = 0.f;

    const int r  = tid >> 2, cb = (tid & 3) * 8;  // A-tile load coords (row, k-base)
    const int kr = tid >> 3, nb = (tid & 7) * 8;  // W-tile load coords (k, col-base)
    const int row_a = m0 + r;

#pragma unroll
    for (int pass = 0; pass < (TWOA ? 2 : 1); ++pass) {
        const ushort* A = (TWOA && pass) ? A2 : A1;
        const float*  W = (TWOA && pass) ? W2g : W1g;
        for (int k0 = 0; k0 < K; k0 += 32) {
            float av[8];
            if (row_a < M) {
                uint4 q = *reinterpret_cast<const uint4*>(A + (size_t)row_a * K + k0 + cb);
                unsigned int u[4] = {q.x, q.y, q.z, q.w};
#pragma unroll
                for (int j = 0; j < 4; ++j) {
                    av[2 * j]     = bf2f((ushort)(u[j] & 0xffffu));
                    av[2 * j + 1] = bf2f((ushort)(u[j] >> 16));
                }
            } else {
#pragma unroll
                for (int j = 0; j < 8; ++j) av[j] = 0.f;
            }
            const float* wp = W + (size_t)(k0 + kr) * NC + n0 + nb;
            float4 w0 = *reinterpret_cast<const float4*>(wp);
            float4 w1 = *reinterpret_cast<const float4*>(wp + 4);

            __syncthreads();
#pragma unroll
            for (int j = 0; j < 8; ++j) As[cb + j][r] = av[j];
            *reinterpret_cast<float4*>(&Ws[kr][nb])     = w0;
            *reinterpret_cast<float4*>(&Ws[kr][nb + 4]) = w1;
            __syncthreads();

#pragma unroll
            for (int kk = 0; kk < 32; ++kk) {
                float4 a = *reinterpret_cast<const float4*>(&As[kk][ty * 4]);
                float4 w = *reinterpret_cast<const float4*>(&Ws[kk][tx * 4]);
                float af[4] = {a.x, a.y, a.z, a.w};
                float wf[4] = {w.x, w.y, w.z, w.w};
#pragma unroll
                for (int i = 0; i < 4; ++i)
#pragma unroll
                    for (int j = 0; j < 4; ++j)
                        acc[i][j] = fmaf(af[i], wf[j], acc[i][j]);
            }
        }
    }

    // epilogue
    float bj[4], sc[4], be[4];
#pragma unroll
    for (int j = 0; j < 4; ++j) {
        int col = n0 + tx * 4 + j;
        bj[j] = bias[col];
        if (ACT == 2) {
            sc[j] = gamma[col] * rsqrtf(1.0f + 1e-5f);
            be[j] = beta[col];
        }
    }
#pragma unroll
    for (int i = 0; i < 4; ++i) {
        int row = m0 + ty * 4 + i;
        if (row >= M) continue;
        float v[4];
#pragma unroll
        for (int j = 0; j < 4; ++j) {
            float t = acc[i][j] + bj[j];
            if (ACT == 2) t = t * sc[j] + be[j];
            if (ACT >= 1) t = fmaxf(t, 0.f);
            v[j] = t;
        }
        if (ACT == 0) {
            float4 o = {v[0], v[1], v[2], v[3]};
            *reinterpret_cast<float4*>(&outf[(size_t)row * NC + n0 + tx * 4]) = o;
        } else {
            ushort4 o;
            o.x = f2bf(v[0]); o.y = f2bf(v[1]); o.z = f2bf(v[2]); o.w = f2bf(v[3]);
            *reinterpret_cast<ushort4*>(&outb[(size_t)row * NC + n0 + tx * 4]) = o;
        }
    }
}

// ---------- launch ----------
extern "C" void kernel_launch(void* const* d_in, const int* in_sizes, int n_in,
                              void* d_out, int out_size, void* d_ws, size_t ws_size,
                              hipStream_t stream) {
    const float* x     = (const float*)d_in[0];
    const int*   src   = (const int*)d_in[1];
    const int*   dst   = (const int*)d_in[2];
    const float* W1s   = (const float*)d_in[3];
    const float* W1n   = (const float*)d_in[4];
    const float* b1    = (const float*)d_in[5];
    const float* W2s   = (const float*)d_in[6];
    const float* W2n   = (const float*)d_in[7];
    const float* b2    = (const float*)d_in[8];
    const float* mW1   = (const float*)d_in[9];
    const float* mb1   = (const float*)d_in[10];
    const float* gamma = (const float*)d_in[11];
    const float* beta  = (const float*)d_in[12];
    const float* mW2   = (const float*)d_in[13];
    const float* mb2   = (const float*)d_in[14];

    const int IN = 128, HID = 256, OUT = 256, MLPH = 256, MLPO = 64;
    const int N = in_sizes[0] / IN;   // 100000
    const int E = in_sizes[1];        // 800000

    // workspace carve (256B aligned)
    char* base = (char*)d_ws;
    size_t o = 0;
    auto alloc = [&](size_t bytes) -> char* {
        o = (o + 255) & ~(size_t)255;
        char* p = base + o;
        o += bytes;
        return p;
    };
    int* deg     = (int*)alloc((size_t)N * 4);
    int* offs    = (int*)alloc((size_t)(N + 1) * 4);
    int* cursor  = (int*)alloc((size_t)N * 4);
    int* bsum    = (int*)alloc(512 * 4);
    int* csr     = (int*)alloc((size_t)E * 4);
    ushort* xb   = (ushort*)alloc((size_t)N * IN * 2);
    ushort* xnb  = (ushort*)alloc((size_t)N * IN * 2);
    ushort* h1   = (ushort*)alloc((size_t)N * HID * 2);
    ushort* h1n  = (ushort*)alloc((size_t)N * HID * 2);
    ushort* h2   = (ushort*)alloc((size_t)N * OUT * 2);
    ushort* tmlp = h1;  // reuse (h1 dead after gemm2)

    const int nb1 = (N + 255) / 256;

    // x -> bf16
    {
        int n4 = N * IN / 4;
        int blocks = (n4 + 255) / 256;
        if (blocks > 2048) blocks = 2048;
        cvt_f32_bf16<<<blocks, 256, 0, stream>>>((const float4*)x, (ushort4*)xb, n4);
    }
    // CSR build
    zero_i32<<<(N + 255) / 256, 256, 0, stream>>>(deg, N);
    deg_kernel<<<(E + 255) / 256, 256, 0, stream>>>(dst, deg, E);
    scan1<<<nb1, 256, 0, stream>>>(deg, offs, bsum, N);
    scan2<<<1, 512, 0, stream>>>(bsum, nb1);
    add_off<<<(N + 1 + 255) / 256, 256, 0, stream>>>(offs, bsum, cursor, N, E);
    fill_csr<<<(E + 255) / 256, 256, 0, stream>>>(src, dst, cursor, csr, E);

    const int gm = (N + 63) / 64;

    // layer 1: agg + fused SAGE GEMM + relu
    agg_mean<128><<<N, 64, 0, stream>>>(xb, offs, csr, xnb);
    gemm_fused<128, 256, true, 1><<<dim3(gm, 4), 256, 0, stream>>>(
        xb, xnb, W1s, W1n, b1, nullptr, nullptr, h1, nullptr, N);

    // layer 2
    agg_mean<256><<<N, 64, 0, stream>>>(h1, offs, csr, h1n);
    gemm_fused<256, 256, true, 1><<<dim3(gm, 4), 256, 0, stream>>>(
        h1, h1n, W2s, W2n, b2, nullptr, nullptr, h2, nullptr, N);

    // MLP: Linear -> BN(eval) -> ReLU   (fused epilogue)
    gemm_fused<256, 256, false, 2><<<dim3(gm, 4), 256, 0, stream>>>(
        h2, nullptr, mW1, nullptr, mb1, gamma, beta, tmlp, nullptr, N);

    // final Linear -> fp32 out
    gemm_fused<256, 64, false, 0><<<dim3(gm, 1), 256, 0, stream>>>(
        tmlp, nullptr, mW2, nullptr, mb2, nullptr, nullptr, nullptr, (float*)d_out, N);
}

// Round 2
// 364.540 us; speedup vs baseline: 2.5747x; 2.5747x over previous
//
#include <hip/hip_runtime.h>
#include <hip/hip_bf16.h>

typedef float v4f __attribute__((ext_vector_type(4)));
typedef short v8s __attribute__((ext_vector_type(8)));

// ---------- helpers ----------
__device__ __forceinline__ float bf2f(ushort u) {
    union { unsigned int i; float f; } v; v.i = ((unsigned int)u) << 16; return v.f;
}
__device__ __forceinline__ ushort f2bf(float f) {
    union { float f; unsigned int i; } v; v.f = f;
    unsigned int x = v.i;
    unsigned int r = (x + 0x7fffu + ((x >> 16) & 1u)) >> 16;   // RNE
    return (ushort)r;
}
__device__ __forceinline__ void gld_lds16(const ushort* g, ushort* l) {
    __builtin_amdgcn_global_load_lds(
        (const __attribute__((address_space(1))) unsigned int*)g,
        (__attribute__((address_space(3))) unsigned int*)l, 16, 0, 0);
}

// ---------- small utility kernels ----------
__global__ void zero_i32(int* p, int n) {
    int i = blockIdx.x * blockDim.x + threadIdx.x;
    if (i < n) p[i] = 0;
}

// x [M][128] fp32 -> dst [M][stride] bf16 (cols 0..127)
__global__ void cvt_strided(const float4* __restrict__ x, ushort* __restrict__ dst,
                            int total, int stride) {
    int idx = blockIdx.x * blockDim.x + threadIdx.x;
    if (idx >= total) return;
    int row = idx >> 5, c4 = idx & 31;
    float4 f = x[idx];
    ushort4 o;
    o.x = f2bf(f.x); o.y = f2bf(f.y); o.z = f2bf(f.z); o.w = f2bf(f.w);
    *reinterpret_cast<ushort4*>(dst + (size_t)row * stride + c4 * 4) = o;
}

// transpose(+concat) weights to bf16 [NC][Kt]:  dst[n][k] = k<K1 ? Wa[k][n] : Wb[k-K1][n]
__global__ void prep_wt(const float* __restrict__ Wa, const float* __restrict__ Wb,
                        ushort* __restrict__ dst, int K1, int Kt, int NC) {
    int idx = blockIdx.x * blockDim.x + threadIdx.x;
    if (idx >= Kt * NC) return;
    int n = idx / Kt, k = idx - n * Kt;
    float v = (k < K1) ? Wa[(size_t)k * NC + n] : Wb[(size_t)(k - K1) * NC + n];
    dst[idx] = f2bf(v);
}

__global__ void deg_kernel(const int* __restrict__ dst, int* __restrict__ deg, int E) {
    int e = blockIdx.x * blockDim.x + threadIdx.x;
    if (e < E) atomicAdd(&deg[dst[e]], 1);
}

__global__ void scan1(const int* __restrict__ deg, int* __restrict__ excl,
                      int* __restrict__ bsum, int N) {
    __shared__ int s[256];
    int tid = threadIdx.x;
    int gid = blockIdx.x * 256 + tid;
    int v = (gid < N) ? deg[gid] : 0;
    s[tid] = v;
    __syncthreads();
    for (int off = 1; off < 256; off <<= 1) {
        int t = (tid >= off) ? s[tid - off] : 0;
        __syncthreads();
        s[tid] += t;
        __syncthreads();
    }
    if (gid < N) excl[gid] = s[tid] - v;
    if (tid == 255) bsum[blockIdx.x] = s[255];
}

__global__ void scan2(int* __restrict__ bsum, int nb) {
    __shared__ int s[512];
    int tid = threadIdx.x;
    int v = (tid < nb) ? bsum[tid] : 0;
    s[tid] = v;
    __syncthreads();
    for (int off = 1; off < 512; off <<= 1) {
        int t = (tid >= off) ? s[tid - off] : 0;
        __syncthreads();
        s[tid] += t;
        __syncthreads();
    }
    if (tid < nb) bsum[tid] = s[tid] - v;
}

__global__ void add_off(int* __restrict__ offs, const int* __restrict__ bsum,
                        int* __restrict__ cursor, int N, int E) {
    int gid = blockIdx.x * blockDim.x + threadIdx.x;
    if (gid < N) {
        int o = offs[gid] + bsum[gid >> 8];
        offs[gid] = o;
        cursor[gid] = o;
    } else if (gid == N) {
        offs[N] = E;
    }
}

__global__ void fill_csr(const int* __restrict__ src, const int* __restrict__ dst,
                         int* __restrict__ cursor, int* __restrict__ csr, int E) {
    int e = blockIdx.x * blockDim.x + threadIdx.x;
    if (e < E) {
        int p = atomicAdd(&cursor[dst[e]], 1);
        csr[p] = src[e];
    }
}

// ---------- mean aggregation (one wave per node); strided src/dst ----------
template <int D>
__global__ void agg_mean(const ushort* __restrict__ h, int hs,
                         const int* __restrict__ off, const int* __restrict__ csr,
                         ushort* __restrict__ out, int os) {
    constexpr int V = D / 64;
    int n = blockIdx.x;
    int lane = threadIdx.x;
    int s = off[n], e = off[n + 1];
    float acc[V];
#pragma unroll
    for (int k = 0; k < V; ++k) acc[k] = 0.f;
    for (int i = s; i < e; ++i) {
        int u = csr[i];
        if constexpr (V == 2) {
            ushort2 q = *reinterpret_cast<const ushort2*>(h + (size_t)u * hs + lane * 2);
            acc[0] += bf2f(q.x); acc[1] += bf2f(q.y);
        } else {
            ushort4 q = *reinterpret_cast<const ushort4*>(h + (size_t)u * hs + lane * 4);
            acc[0] += bf2f(q.x); acc[1] += bf2f(q.y);
            acc[2] += bf2f(q.z); acc[3] += bf2f(q.w);
        }
    }
    float inv = (e > s) ? 1.0f / (float)(e - s) : 1.0f;
    if constexpr (V == 2) {
        ushort2 o;
        o.x = f2bf(acc[0] * inv); o.y = f2bf(acc[1] * inv);
        *reinterpret_cast<ushort2*>(out + (size_t)n * os + lane * 2) = o;
    } else {
        ushort4 o;
        o.x = f2bf(acc[0] * inv); o.y = f2bf(acc[1] * inv);
        o.z = f2bf(acc[2] * inv); o.w = f2bf(acc[3] * inv);
        *reinterpret_cast<ushort4*>(out + (size_t)n * os + lane * 4) = o;
    }
}

// ---------- MFMA GEMM:  out = act( A @ Wt^T + bias ) ----------
// A: bf16 [M_pad][K] row-major (row stride == K).  Wt: bf16 [NC][K] row-major.
// Tile BM=128 x BN, BK=32. 4 waves in 2x2; per-wave 64 x BN/2.
// ACT: 0 = none->fp32, 1 = relu->bf16, 2 = BN+relu->bf16.  OS = out row stride.
template <int K, int NC, int BN, int ACT>
__launch_bounds__(256)
__global__ void gemm_mfma(const ushort* __restrict__ A, const ushort* __restrict__ Wt,
                          const float* __restrict__ bias, const float* __restrict__ gamma,
                          const float* __restrict__ beta,
                          ushort* __restrict__ outb, float* __restrict__ outf,
                          int M, int OS) {
    constexpr int BM = 128, BK = 32;
    constexpr int NJ = BN / 32;
    __shared__ ushort lds[(BM + BN) * BK];
    ushort* Bs = lds + BM * BK;

    const int tid = threadIdx.x;
    const int lane = tid & 63, wid = tid >> 6;
    const int wm = wid & 1, wn = wid >> 1;
    const int m0 = blockIdx.x * BM, n0 = blockIdx.y * BN;

    const int srow = wid * 16 + (lane >> 2);   // staging row within a 64-row issue
    const int sq   = lane & 3;                 // 16B slot within 64B row
    const int fr = lane & 15, fg = lane >> 4;  // fragment row / k-group

    v4f acc[4][NJ];
#pragma unroll
    for (int i = 0; i < 4; ++i)
#pragma unroll
        for (int j = 0; j < NJ; ++j) acc[i][j] = (v4f)0.f;

    for (int k0 = 0; k0 < K; k0 += BK) {
        __syncthreads();  // previous tile fully consumed
        {   // A staging: 2 x 64 rows, swizzled source, linear LDS dest
            int r0 = srow, r1 = srow + 64;
            gld_lds16(A + (size_t)(m0 + r0) * K + k0 + ((sq ^ (r0 & 3)) << 3),
                      lds + (size_t)r0 * 32 + sq * 8);
            gld_lds16(A + (size_t)(m0 + r1) * K + k0 + ((sq ^ (r1 & 3)) << 3),
                      lds + (size_t)r1 * 32 + sq * 8);
        }
        {   // B staging
            int r0 = srow;
            gld_lds16(Wt + (size_t)(n0 + r0) * K + k0 + ((sq ^ (r0 & 3)) << 3),
                      Bs + (size_t)r0 * 32 + sq * 8);
            if (BN == 128) {
                int r1 = srow + 64;
                gld_lds16(Wt + (size_t)(n0 + r1) * K + k0 + ((sq ^ (r1 & 3)) << 3),
                          Bs + (size_t)r1 * 32 + sq * 8);
            }
        }
        __syncthreads();  // drains vmcnt -> tile ready

        v8s a[4], b[NJ];
#pragma unroll
        for (int mi = 0; mi < 4; ++mi) {
            int row = wm * 64 + mi * 16 + fr;
            a[mi] = *reinterpret_cast<const v8s*>(lds + (size_t)row * 32 + ((fg ^ (row & 3)) << 3));
        }
#pragma unroll
        for (int nj = 0; nj < NJ; ++nj) {
            int row = wn * (BN / 2) + nj * 16 + fr;
            b[nj] = *reinterpret_cast<const v8s*>(Bs + (size_t)row * 32 + ((fg ^ (row & 3)) << 3));
        }
#pragma unroll
        for (int mi = 0; mi < 4; ++mi)
#pragma unroll
            for (int nj = 0; nj < NJ; ++nj)
                acc[mi][nj] = __builtin_amdgcn_mfma_f32_16x16x32_bf16(a[mi], b[nj], acc[mi][nj], 0, 0, 0);
    }

    // epilogue
    float bj[NJ], sc[NJ], be[NJ];
#pragma unroll
    for (int nj = 0; nj < NJ; ++nj) {
        int col = n0 + wn * (BN / 2) + nj * 16 + fr;
        bj[nj] = bias[col];
        if (ACT == 2) { sc[nj] = gamma[col] * rsqrtf(1.0f + 1e-5f); be[nj] = beta[col]; }
    }
#pragma unroll
    for (int mi = 0; mi < 4; ++mi) {
#pragma unroll
        for (int r = 0; r < 4; ++r) {
            int row = m0 + wm * 64 + mi * 16 + fg * 4 + r;
            if (row < M) {
#pragma unroll
                for (int nj = 0; nj < NJ; ++nj) {
                    int col = n0 + wn * (BN / 2) + nj * 16 + fr;
                    float t = acc[mi][nj][r] + bj[nj];
                    if (ACT == 2) t = t * sc[nj] + be[nj];
                    if (ACT >= 1) t = fmaxf(t, 0.f);
                    if (ACT == 0) outf[(size_t)row * OS + col] = t;
                    else          outb[(size_t)row * OS + col] = f2bf(t);
                }
            }
        }
    }
}

// ---------- launch ----------
extern "C" void kernel_launch(void* const* d_in, const int* in_sizes, int n_in,
                              void* d_out, int out_size, void* d_ws, size_t ws_size,
                              hipStream_t stream) {
    const float* x     = (const float*)d_in[0];
    const int*   src   = (const int*)d_in[1];
    const int*   dstv  = (const int*)d_in[2];
    const float* W1s   = (const float*)d_in[3];
    const float* W1n   = (const float*)d_in[4];
    const float* b1    = (const float*)d_in[5];
    const float* W2s   = (const float*)d_in[6];
    const float* W2n   = (const float*)d_in[7];
    const float* b2    = (const float*)d_in[8];
    const float* mW1   = (const float*)d_in[9];
    const float* mb1   = (const float*)d_in[10];
    const float* gamma = (const float*)d_in[11];
    const float* beta  = (const float*)d_in[12];
    const float* mW2   = (const float*)d_in[13];
    const float* mb2   = (const float*)d_in[14];

    const int IN = 128, HID = 256, OUT = 256;
    const int N = in_sizes[0] / IN;   // 100000
    const int E = in_sizes[1];        // 800000
    const int GM = (N + 127) / 128;   // 782
    const int M_pad = GM * 128;       // 100096

    char* base = (char*)d_ws;
    size_t o = 0;
    auto alloc = [&](size_t bytes) -> char* {
        o = (o + 255) & ~(size_t)255;
        char* p = base + o;
        o += bytes;
        return p;
    };
    int* deg    = (int*)alloc((size_t)N * 4);
    int* offs   = (int*)alloc((size_t)(N + 1) * 4);
    int* cursor = (int*)alloc((size_t)N * 4);
    int* bsum   = (int*)alloc(512 * 4);
    int* csr    = (int*)alloc((size_t)E * 4);
    ushort* Wt1  = (ushort*)alloc((size_t)256 * 256 * 2);   // [256 n][256 k] = [W1s;W1n]^T
    ushort* Wt2  = (ushort*)alloc((size_t)256 * 512 * 2);   // [256 n][512 k]
    ushort* Wtm1 = (ushort*)alloc((size_t)256 * 256 * 2);
    ushort* Wtm2 = (ushort*)alloc((size_t)64 * 256 * 2);
    ushort* hcat0 = (ushort*)alloc((size_t)M_pad * 256 * 2); // [x | xagg]; later reused as h2
    ushort* h1cat = (ushort*)alloc((size_t)M_pad * 512 * 2); // [h1 | h1agg]; later reused as tmlp

    ushort* h2   = hcat0;   // hcat0 dead after gemm1
    ushort* tmlp = h1cat;   // h1cat dead after gemm2

    // ---- weight prep (tiny) ----
    prep_wt<<<(256 * 256 + 255) / 256, 256, 0, stream>>>(W1s, W1n, Wt1, 128, 256, 256);
    prep_wt<<<(256 * 512 + 255) / 256, 256, 0, stream>>>(W2s, W2n, Wt2, 256, 512, 256);
    prep_wt<<<(256 * 256 + 255) / 256, 256, 0, stream>>>(mW1, mW1, Wtm1, 256, 256, 256);
    prep_wt<<<(64 * 256 + 255) / 256, 256, 0, stream>>>(mW2, mW2, Wtm2, 256, 256, 64);

    // ---- x -> bf16 into hcat0 cols 0..127 ----
    cvt_strided<<<(N * 32 + 255) / 256, 256, 0, stream>>>((const float4*)x, hcat0, N * 32, 256);

    // ---- CSR build ----
    const int nb1 = (N + 255) / 256;
    zero_i32<<<nb1, 256, 0, stream>>>(deg, N);
    deg_kernel<<<(E + 255) / 256, 256, 0, stream>>>(dstv, deg, E);
    scan1<<<nb1, 256, 0, stream>>>(deg, offs, bsum, N);
    scan2<<<1, 512, 0, stream>>>(bsum, nb1);
    add_off<<<(N + 1 + 255) / 256, 256, 0, stream>>>(offs, bsum, cursor, N, E);
    fill_csr<<<(E + 255) / 256, 256, 0, stream>>>(src, dstv, cursor, csr, E);

    // ---- layer 1 ----
    agg_mean<128><<<N, 64, 0, stream>>>(hcat0, 256, offs, csr, hcat0 + 128, 256);
    gemm_mfma<256, 256, 128, 1><<<dim3(GM, 2), 256, 0, stream>>>(
        hcat0, Wt1, b1, nullptr, nullptr, h1cat, nullptr, N, 512);

    // ---- layer 2 ----
    agg_mean<256><<<N, 64, 0, stream>>>(h1cat, 512, offs, csr, h1cat + 256, 512);
    gemm_mfma<512, 256, 128, 1><<<dim3(GM, 2), 256, 0, stream>>>(
        h1cat, Wt2, b2, nullptr, nullptr, h2, nullptr, N, 256);

    // ---- MLP1: Linear -> BN(eval) -> ReLU ----
    gemm_mfma<256, 256, 128, 2><<<dim3(GM, 2), 256, 0, stream>>>(
        h2, Wtm1, mb1, gamma, beta, tmlp, nullptr, N, 256);

    // ---- MLP2: Linear -> fp32 out ----
    gemm_mfma<256, 64, 64, 0><<<dim3(GM, 1), 256, 0, stream>>>(
        tmlp, Wtm2, mb2, nullptr, nullptr, nullptr, (float*)d_out, N, 64);
}

// Round 3
// 321.336 us; speedup vs baseline: 2.9208x; 1.1344x over previous
//
#include <hip/hip_runtime.h>
#include <hip/hip_bf16.h>

typedef float v4f __attribute__((ext_vector_type(4)));
typedef short v8s __attribute__((ext_vector_type(8)));

// ---------- helpers ----------
__device__ __forceinline__ float bf2f(ushort u) {
    union { unsigned int i; float f; } v; v.i = ((unsigned int)u) << 16; return v.f;
}
__device__ __forceinline__ ushort f2bf(float f) {
    union { float f; unsigned int i; } v; v.f = f;
    unsigned int x = v.i;
    unsigned int r = (x + 0x7fffu + ((x >> 16) & 1u)) >> 16;   // RNE
    return (ushort)r;
}
__device__ __forceinline__ void gld_lds16(const ushort* g, ushort* l) {
    __builtin_amdgcn_global_load_lds(
        (const __attribute__((address_space(1))) unsigned int*)g,
        (__attribute__((address_space(3))) unsigned int*)l, 16, 0, 0);
}

// ---------- small utility kernels ----------
__global__ void zero_i32(int* p, int n) {
    int i = blockIdx.x * blockDim.x + threadIdx.x;
    if (i < n) p[i] = 0;
}

// x [M][128] fp32 -> dst [M][stride] bf16 (cols 0..127)
__global__ void cvt_strided(const float4* __restrict__ x, ushort* __restrict__ dst,
                            int total, int stride) {
    int idx = blockIdx.x * blockDim.x + threadIdx.x;
    if (idx >= total) return;
    int row = idx >> 5, c4 = idx & 31;
    float4 f = x[idx];
    ushort4 o;
    o.x = f2bf(f.x); o.y = f2bf(f.y); o.z = f2bf(f.z); o.w = f2bf(f.w);
    *reinterpret_cast<ushort4*>(dst + (size_t)row * stride + c4 * 4) = o;
}

// transpose(+concat) weights to bf16 [NC][Kt]:  dst[n][k] = k<K1 ? Wa[k][n] : Wb[k-K1][n]
__global__ void prep_wt(const float* __restrict__ Wa, const float* __restrict__ Wb,
                        ushort* __restrict__ dst, int K1, int Kt, int NC) {
    int idx = blockIdx.x * blockDim.x + threadIdx.x;
    if (idx >= Kt * NC) return;
    int n = idx / Kt, k = idx - n * Kt;
    float v = (k < K1) ? Wa[(size_t)k * NC + n] : Wb[(size_t)(k - K1) * NC + n];
    dst[idx] = f2bf(v);
}

__global__ void deg_kernel(const int* __restrict__ dst, int* __restrict__ deg, int E) {
    int e = blockIdx.x * blockDim.x + threadIdx.x;
    if (e < E) atomicAdd(&deg[dst[e]], 1);
}

__global__ void scan1(const int* __restrict__ deg, int* __restrict__ excl,
                      int* __restrict__ bsum, int N) {
    __shared__ int s[256];
    int tid = threadIdx.x;
    int gid = blockIdx.x * 256 + tid;
    int v = (gid < N) ? deg[gid] : 0;
    s[tid] = v;
    __syncthreads();
    for (int off = 1; off < 256; off <<= 1) {
        int t = (tid >= off) ? s[tid - off] : 0;
        __syncthreads();
        s[tid] += t;
        __syncthreads();
    }
    if (gid < N) excl[gid] = s[tid] - v;
    if (tid == 255) bsum[blockIdx.x] = s[255];
}

__global__ void scan2(int* __restrict__ bsum, int nb) {
    __shared__ int s[512];
    int tid = threadIdx.x;
    int v = (tid < nb) ? bsum[tid] : 0;
    s[tid] = v;
    __syncthreads();
    for (int off = 1; off < 512; off <<= 1) {
        int t = (tid >= off) ? s[tid - off] : 0;
        __syncthreads();
        s[tid] += t;
        __syncthreads();
    }
    if (tid < nb) bsum[tid] = s[tid] - v;
}

__global__ void add_off(int* __restrict__ offs, const int* __restrict__ bsum,
                        int* __restrict__ cursor, int N, int E) {
    int gid = blockIdx.x * blockDim.x + threadIdx.x;
    if (gid < N) {
        int o = offs[gid] + bsum[gid >> 8];
        offs[gid] = o;
        cursor[gid] = o;
    } else if (gid == N) {
        offs[N] = E;
    }
}

__global__ void fill_csr(const int* __restrict__ src, const int* __restrict__ dst,
                         int* __restrict__ cursor, int* __restrict__ csr, int E) {
    int e = blockIdx.x * blockDim.x + threadIdx.x;
    if (e < E) {
        int p = atomicAdd(&cursor[dst[e]], 1);
        csr[p] = src[e];
    }
}

// ---------- mean aggregation (one wave per node); 4-way unrolled gather ----------
template <int D>
__global__ void agg_mean(const ushort* __restrict__ h, int hs,
                         const int* __restrict__ off, const int* __restrict__ csr,
                         ushort* __restrict__ out, int os) {
    constexpr int V = D / 64;  // 2 or 4
    int n = blockIdx.x;
    int lane = threadIdx.x;
    int s = off[n], e = off[n + 1];
    float acc[V];
#pragma unroll
    for (int k = 0; k < V; ++k) acc[k] = 0.f;

    int i = s;
    for (; i + 4 <= e; i += 4) {
        int u0 = csr[i], u1 = csr[i + 1], u2 = csr[i + 2], u3 = csr[i + 3];
        if constexpr (V == 2) {
            ushort2 q0 = *reinterpret_cast<const ushort2*>(h + (size_t)u0 * hs + lane * 2);
            ushort2 q1 = *reinterpret_cast<const ushort2*>(h + (size_t)u1 * hs + lane * 2);
            ushort2 q2 = *reinterpret_cast<const ushort2*>(h + (size_t)u2 * hs + lane * 2);
            ushort2 q3 = *reinterpret_cast<const ushort2*>(h + (size_t)u3 * hs + lane * 2);
            acc[0] += bf2f(q0.x) + bf2f(q1.x) + bf2f(q2.x) + bf2f(q3.x);
            acc[1] += bf2f(q0.y) + bf2f(q1.y) + bf2f(q2.y) + bf2f(q3.y);
        } else {
            ushort4 q0 = *reinterpret_cast<const ushort4*>(h + (size_t)u0 * hs + lane * 4);
            ushort4 q1 = *reinterpret_cast<const ushort4*>(h + (size_t)u1 * hs + lane * 4);
            ushort4 q2 = *reinterpret_cast<const ushort4*>(h + (size_t)u2 * hs + lane * 4);
            ushort4 q3 = *reinterpret_cast<const ushort4*>(h + (size_t)u3 * hs + lane * 4);
            acc[0] += bf2f(q0.x) + bf2f(q1.x) + bf2f(q2.x) + bf2f(q3.x);
            acc[1] += bf2f(q0.y) + bf2f(q1.y) + bf2f(q2.y) + bf2f(q3.y);
            acc[2] += bf2f(q0.z) + bf2f(q1.z) + bf2f(q2.z) + bf2f(q3.z);
            acc[3] += bf2f(q0.w) + bf2f(q1.w) + bf2f(q2.w) + bf2f(q3.w);
        }
    }
    for (; i < e; ++i) {
        int u = csr[i];
        if constexpr (V == 2) {
            ushort2 q = *reinterpret_cast<const ushort2*>(h + (size_t)u * hs + lane * 2);
            acc[0] += bf2f(q.x); acc[1] += bf2f(q.y);
        } else {
            ushort4 q = *reinterpret_cast<const ushort4*>(h + (size_t)u * hs + lane * 4);
            acc[0] += bf2f(q.x); acc[1] += bf2f(q.y);
            acc[2] += bf2f(q.z); acc[3] += bf2f(q.w);
        }
    }
    float inv = (e > s) ? 1.0f / (float)(e - s) : 1.0f;
    if constexpr (V == 2) {
        ushort2 o;
        o.x = f2bf(acc[0] * inv); o.y = f2bf(acc[1] * inv);
        *reinterpret_cast<ushort2*>(out + (size_t)n * os + lane * 2) = o;
    } else {
        ushort4 o;
        o.x = f2bf(acc[0] * inv); o.y = f2bf(acc[1] * inv);
        o.z = f2bf(acc[2] * inv); o.w = f2bf(acc[3] * inv);
        *reinterpret_cast<ushort4*>(out + (size_t)n * os + lane * 4) = o;
    }
}

// ---------- MFMA GEMM (full-width tile, 2-phase double-buffered) ----------
// out = act( A @ Wt^T + bias ).  A: bf16 [M_pad][K] rs=K.  Wt: bf16 [BN][K].
// BM=128 x BN (==NC), BK=32, 512 threads = 8 waves (2m x 4n), per-wave 64 x BN/4.
// ACT: 0 = none->fp32, 1 = relu->bf16, 2 = BN+relu->bf16.  OS = out row stride.
template <int K, int BN, int ACT>
__launch_bounds__(512)
__global__ void gemm_mfma(const ushort* __restrict__ A, const ushort* __restrict__ Wt,
                          const float* __restrict__ bias, const float* __restrict__ gamma,
                          const float* __restrict__ beta,
                          ushort* __restrict__ outb, float* __restrict__ outf,
                          int M, int OS) {
    constexpr int BM = 128, BK = 32;
    constexpr int NJ = BN / 64;          // col frags per wave
    constexpr int NT = K / BK;
    constexpr int ASZ = BM * BK;         // ushorts
    constexpr int BSZ = BN * BK;
    __shared__ ushort lds[2 * (ASZ + BSZ)];

    const int tid = threadIdx.x;
    const int lane = tid & 63, wid = tid >> 6;
    const int wm = wid & 1, wn = wid >> 1;     // 2 x 4 wave grid
    const int m0 = blockIdx.x * BM;
    const int fr = lane & 15, fg = lane >> 4;

    const int srow = tid >> 2;                 // staging row (0..127)
    const int sslot = tid & 3;                 // 16B slot within 64B row

    v4f acc[4][NJ];
#pragma unroll
    for (int i = 0; i < 4; ++i)
#pragma unroll
        for (int j = 0; j < NJ; ++j) acc[i][j] = (v4f)0.f;

    auto stage = [&](int buf, int k0) {
        ushort* Ab = lds + buf * (ASZ + BSZ);
        ushort* Bb = Ab + ASZ;
        gld_lds16(A + (size_t)(m0 + srow) * K + k0 + ((sslot ^ (srow & 3)) << 3),
                  Ab + tid * 8);
        if constexpr (BN >= 128) {
#pragma unroll
            for (int i = 0; i < BN / 128; ++i) {
                int br = srow + i * 128;
                gld_lds16(Wt + (size_t)br * K + k0 + ((sslot ^ (br & 3)) << 3),
                          Bb + i * 4096 + tid * 8);
            }
        } else {
            if (tid < BN * 4)
                gld_lds16(Wt + (size_t)srow * K + k0 + ((sslot ^ (srow & 3)) << 3),
                          Bb + tid * 8);
        }
    };

    stage(0, 0);
    __syncthreads();
    int cur = 0;
    for (int t = 0; t < NT; ++t) {
        if (t + 1 < NT) stage(cur ^ 1, (t + 1) * BK);

        const ushort* Ab = lds + cur * (ASZ + BSZ);
        const ushort* Bb = Ab + ASZ;
        v8s a[4], b[NJ];
#pragma unroll
        for (int mi = 0; mi < 4; ++mi) {
            int row = wm * 64 + mi * 16 + fr;
            a[mi] = *reinterpret_cast<const v8s*>(Ab + row * 32 + ((fg ^ (row & 3)) << 3));
        }
#pragma unroll
        for (int nj = 0; nj < NJ; ++nj) {
            int row = wn * (BN / 4) + nj * 16 + fr;
            b[nj] = *reinterpret_cast<const v8s*>(Bb + row * 32 + ((fg ^ (row & 3)) << 3));
        }
#pragma unroll
        for (int mi = 0; mi < 4; ++mi)
#pragma unroll
            for (int nj = 0; nj < NJ; ++nj)
                acc[mi][nj] = __builtin_amdgcn_mfma_f32_16x16x32_bf16(a[mi], b[nj], acc[mi][nj], 0, 0, 0);

        if (t + 1 < NT) { __syncthreads(); cur ^= 1; }
    }

    // epilogue
    float bj[NJ], sc[NJ], be[NJ];
#pragma unroll
    for (int nj = 0; nj < NJ; ++nj) {
        int col = wn * (BN / 4) + nj * 16 + fr;
        bj[nj] = bias[col];
        if (ACT == 2) { sc[nj] = gamma[col] * rsqrtf(1.0f + 1e-5f); be[nj] = beta[col]; }
    }
#pragma unroll
    for (int mi = 0; mi < 4; ++mi) {
#pragma unroll
        for (int r = 0; r < 4; ++r) {
            int row = m0 + wm * 64 + mi * 16 + fg * 4 + r;
            if (row < M) {
#pragma unroll
                for (int nj = 0; nj < NJ; ++nj) {
                    int col = wn * (BN / 4) + nj * 16 + fr;
                    float t = acc[mi][nj][r] + bj[nj];
                    if (ACT == 2) t = t * sc[nj] + be[nj];
                    if (ACT >= 1) t = fmaxf(t, 0.f);
                    if (ACT == 0) outf[(size_t)row * OS + col] = t;
                    else          outb[(size_t)row * OS + col] = f2bf(t);
                }
            }
        }
    }
}

// ---------- launch ----------
extern "C" void kernel_launch(void* const* d_in, const int* in_sizes, int n_in,
                              void* d_out, int out_size, void* d_ws, size_t ws_size,
                              hipStream_t stream) {
    const float* x     = (const float*)d_in[0];
    const int*   src   = (const int*)d_in[1];
    const int*   dstv  = (const int*)d_in[2];
    const float* W1s   = (const float*)d_in[3];
    const float* W1n   = (const float*)d_in[4];
    const float* b1    = (const float*)d_in[5];
    const float* W2s   = (const float*)d_in[6];
    const float* W2n   = (const float*)d_in[7];
    const float* b2    = (const float*)d_in[8];
    const float* mW1   = (const float*)d_in[9];
    const float* mb1   = (const float*)d_in[10];
    const float* gamma = (const float*)d_in[11];
    const float* beta  = (const float*)d_in[12];
    const float* mW2   = (const float*)d_in[13];
    const float* mb2   = (const float*)d_in[14];

    const int IN = 128;
    const int N = in_sizes[0] / IN;   // 100000
    const int E = in_sizes[1];        // 800000
    const int GM = (N + 127) / 128;   // 782
    const int M_pad = GM * 128;       // 100096

    char* base = (char*)d_ws;
    size_t o = 0;
    auto alloc = [&](size_t bytes) -> char* {
        o = (o + 255) & ~(size_t)255;
        char* p = base + o;
        o += bytes;
        return p;
    };
    int* deg    = (int*)alloc((size_t)N * 4);
    int* offs   = (int*)alloc((size_t)(N + 1) * 4);
    int* cursor = (int*)alloc((size_t)N * 4);
    int* bsum   = (int*)alloc(512 * 4);
    int* csr    = (int*)alloc((size_t)E * 4);
    ushort* Wt1  = (ushort*)alloc((size_t)256 * 256 * 2);   // [256 n][256 k] = [W1s;W1n]^T
    ushort* Wt2  = (ushort*)alloc((size_t)256 * 512 * 2);   // [256 n][512 k]
    ushort* Wtm1 = (ushort*)alloc((size_t)256 * 256 * 2);
    ushort* Wtm2 = (ushort*)alloc((size_t)64 * 256 * 2);
    ushort* hcat0 = (ushort*)alloc((size_t)M_pad * 256 * 2); // [x | xagg]; later reused as h2
    ushort* h1cat = (ushort*)alloc((size_t)M_pad * 512 * 2); // [h1 | h1agg]; later reused as tmlp

    ushort* h2   = hcat0;   // hcat0 dead after gemm1
    ushort* tmlp = h1cat;   // h1cat dead after gemm2

    // ---- weight prep (tiny) ----
    prep_wt<<<(256 * 256 + 255) / 256, 256, 0, stream>>>(W1s, W1n, Wt1, 128, 256, 256);
    prep_wt<<<(256 * 512 + 255) / 256, 256, 0, stream>>>(W2s, W2n, Wt2, 256, 512, 256);
    prep_wt<<<(256 * 256 + 255) / 256, 256, 0, stream>>>(mW1, mW1, Wtm1, 256, 256, 256);
    prep_wt<<<(64 * 256 + 255) / 256, 256, 0, stream>>>(mW2, mW2, Wtm2, 256, 256, 64);

    // ---- x -> bf16 into hcat0 cols 0..127 ----
    cvt_strided<<<(N * 32 + 255) / 256, 256, 0, stream>>>((const float4*)x, hcat0, N * 32, 256);

    // ---- CSR build ----
    const int nb1 = (N + 255) / 256;
    zero_i32<<<nb1, 256, 0, stream>>>(deg, N);
    deg_kernel<<<(E + 255) / 256, 256, 0, stream>>>(dstv, deg, E);
    scan1<<<nb1, 256, 0, stream>>>(deg, offs, bsum, N);
    scan2<<<1, 512, 0, stream>>>(bsum, nb1);
    add_off<<<(N + 1 + 255) / 256, 256, 0, stream>>>(offs, bsum, cursor, N, E);
    fill_csr<<<(E + 255) / 256, 256, 0, stream>>>(src, dstv, cursor, csr, E);

    // ---- layer 1 ----
    agg_mean<128><<<N, 64, 0, stream>>>(hcat0, 256, offs, csr, hcat0 + 128, 256);
    gemm_mfma<256, 256, 1><<<GM, 512, 0, stream>>>(
        hcat0, Wt1, b1, nullptr, nullptr, h1cat, nullptr, N, 512);

    // ---- layer 2 ----
    agg_mean<256><<<N, 64, 0, stream>>>(h1cat, 512, offs, csr, h1cat + 256, 512);
    gemm_mfma<512, 256, 1><<<GM, 512, 0, stream>>>(
        h1cat, Wt2, b2, nullptr, nullptr, h2, nullptr, N, 256);

    // ---- MLP1: Linear -> BN(eval) -> ReLU ----
    gemm_mfma<256, 256, 2><<<GM, 512, 0, stream>>>(
        h2, Wtm1, mb1, gamma, beta, tmlp, nullptr, N, 256);

    // ---- MLP2: Linear -> fp32 out ----
    gemm_mfma<256, 64, 0><<<GM, 512, 0, stream>>>(
        tmlp, Wtm2, mb2, nullptr, nullptr, nullptr, (float*)d_out, N, 64);
}